// Round 4
// baseline (380.041 us; speedup 1.0000x reference)
//
#include <hip/hip_runtime.h>
#include <math.h>

#define NA 5
#define HH 76
#define WW 76
#define HWSZ (HH * WW)          // 5776
#define HW4 (HWSZ / 4)          // 1444 float4-groups per plane
#define HALF4 (HW4 / 2)         // 722 groups per half-plane (38 rows)
#define NBLK (512 * NA * 2)     // 5120 main-kernel blocks (half-plane each)
#define OBJECT_SCALE 5.0f
#define SIL_THRESH 0.6f

// ws layout (floats):
//   [REC_OFF + b*REC_STRIDE ...): per-batch records (512 * 12 floats)
//   [PART_OFF + blk*8 ...): per-block partial sums (5 used, 8 stride = 32 B slots)
// record: 0:gx 1:gy 2:gw 3:gh 4:tx 5:ty 6:tw 7:th 8:best(int) 9:gi(int) 10:gj(int) 11:pad
#define REC_OFF 16
#define REC_STRIDE 12
#define PART_OFF 8192

__constant__ float ANC_W[NA] = {0.57273f, 1.87446f, 3.33843f, 7.88282f, 9.77052f};
__constant__ float ANC_H[NA] = {0.677385f, 2.06253f, 5.47434f, 3.52778f, 9.16828f};

typedef float v4f __attribute__((ext_vector_type(4)));

__global__ void prep_kernel(const float* __restrict__ target, float* __restrict__ ws, int bs) {
    int b = threadIdx.x;
    if (b >= bs) return;
    float gx = target[b * 4 + 0] * (float)WW;
    float gy = target[b * 4 + 1] * (float)HH;
    float gw = target[b * 4 + 2] * (float)WW;
    float gh = target[b * 4 + 3] * (float)HH;
    // best anchor: IoU of (0,0,gw,gh) vs (0,0,aw,ah) reduces to aligned-box IoU
    int best = 0;
    float bestv = -1.0f;
#pragma unroll
    for (int a = 0; a < NA; ++a) {
        float aw = ANC_W[a], ah = ANC_H[a];
        float inter = fminf(gw, aw) * fminf(gh, ah);
        float uni = gw * gh + aw * ah - inter;
        float iou = inter / uni;
        if (iou > bestv) { bestv = iou; best = a; }   // first-max wins ties (matches argmax)
    }
    int gi = (int)gx;
    int gj = (int)gy;
    float* r = ws + REC_OFF + b * REC_STRIDE;
    r[0] = gx; r[1] = gy; r[2] = gw; r[3] = gh;
    r[4] = gx - (float)gi;
    r[5] = gy - (float)gj;
    r[6] = logf(gw / ANC_W[best]);
    r[7] = logf(gh / ANC_H[best]);
    ((int*)r)[8] = best;
    ((int*)r)[9] = gi;
    ((int*)r)[10] = gj;
}

__device__ __forceinline__ float sigmoidf_fast(float x) {
    return 1.0f / (1.0f + __expf(-x));
}

struct GtCtx {
    float gxm, gxM, gym, gyM, gw, gh, garea;
    float anw, anh;
    float tx_s, ty_s, tw_s, th_s;
    int gi;
};

__device__ __forceinline__ void proc4(v4f px, v4f py, v4f pw, v4f ph, v4f pc,
                                      int i0, int j, bool rowhit, const GtCtx& c,
                                      float& ax, float& ay, float& aw_, float& ah_, float& ac) {
#pragma unroll
    for (int k = 0; k < 4; ++k) {
        float sx = sigmoidf_fast(px[k]);
        float sy = sigmoidf_fast(py[k]);
        float sc = sigmoidf_fast(pc[k]);
        float bw = __expf(pw[k]) * c.anw;
        float bh = __expf(ph[k]) * c.anh;
        float bx = sx + (float)(i0 + k);
        float by = sy + (float)j;
        // IoU(gt, pred-box) — divide-free except at the 1-per-batch special cell
        float mx = fminf(c.gxm, bx - bw * 0.5f);
        float Mx = fmaxf(c.gxM, bx + bw * 0.5f);
        float my = fminf(c.gym, by - bh * 0.5f);
        float My = fmaxf(c.gyM, by + bh * 0.5f);
        float cw = c.gw + bw - (Mx - mx);
        float ch = c.gh + bh - (My - my);
        float carea = (cw <= 0.f || ch <= 0.f) ? 0.f : cw * ch;
        float uarea = c.garea + bw * bh - carea;   // > 0 always
        // iou > SIL_THRESH  <=>  carea > SIL_THRESH * uarea
        float cmask = (carea > SIL_THRESH * uarea) ? 0.f : 1.f;
        float tx = 0.5f, ty = 0.5f, tw = 0.f, th = 0.f, tconf = 0.f;
        if (rowhit && (i0 + k) == c.gi) {
            cmask = OBJECT_SCALE;
            tx = c.tx_s; ty = c.ty_s; tw = c.tw_s; th = c.th_s;
            tconf = carea / uarea;   // iou_t == iou_all at the responsible cell
        }
        float dx = sx - tx, dy = sy - ty;
        float dw = pw[k] - tw, dh = ph[k] - th;
        float dc = sc - tconf;
        ax += dx * dx;
        ay += dy * dy;
        aw_ += dw * dw;
        ah_ += dh * dh;
        ac += cmask * dc * dc;
    }
}

// One block per half (b, a) plane: grid.x == bs * NA * 2 == 5120.
__global__ __launch_bounds__(256) void
region_loss_main(const float* __restrict__ pred, float* __restrict__ ws) {
    const int blk = blockIdx.x;
    const int ba = blk >> 1;           // (b, a) plane
    const int half = blk & 1;
    const int b  = ba / NA;
    const int a  = ba - b * NA;

    // per-batch record: uniform per block, cached
    const float* rec = ws + REC_OFF + b * REC_STRIDE;
    GtCtx c;
    {
        float gx = rec[0], gy = rec[1];
        c.gw = rec[2]; c.gh = rec[3];
        c.tx_s = rec[4]; c.ty_s = rec[5]; c.tw_s = rec[6]; c.th_s = rec[7];
        c.gi = ((const int*)rec)[9];
        c.gxm = gx - c.gw * 0.5f; c.gxM = gx + c.gw * 0.5f;
        c.gym = gy - c.gh * 0.5f; c.gyM = gy + c.gh * 0.5f;
        c.garea = c.gw * c.gh;
        c.anw = ANC_W[a]; c.anh = ANC_H[a];
    }
    const int best = ((const int*)rec)[8];
    const int gj   = ((const int*)rec)[10];
    const bool anchit = (a == best);

    const float* base = pred + (size_t)ba * 5 * HWSZ;
    const int rbeg = half * HALF4;
    const int rend = rbeg + HALF4;
    float ax = 0.f, ay = 0.f, aw_ = 0.f, ah_ = 0.f, ac = 0.f;

    for (int r = rbeg + threadIdx.x; r < rend; r += 512) {
        const int e0 = r * 4;
        const int j  = r / 19;            // e0 / 76, exact since 76 = 4*19
        const int i0 = e0 - j * WW;
        v4f px = __builtin_nontemporal_load((const v4f*)(base + e0));
        v4f py = __builtin_nontemporal_load((const v4f*)(base + HWSZ + e0));
        v4f pw = __builtin_nontemporal_load((const v4f*)(base + 2 * HWSZ + e0));
        v4f ph = __builtin_nontemporal_load((const v4f*)(base + 3 * HWSZ + e0));
        v4f pc = __builtin_nontemporal_load((const v4f*)(base + 4 * HWSZ + e0));

        const int r2 = r + 256;
        const bool has2 = r2 < rend;
        v4f qx = {0,0,0,0}, qy = {0,0,0,0}, qw = {0,0,0,0}, qh = {0,0,0,0}, qc = {0,0,0,0};
        int j2 = 0, i02 = 0;
        if (has2) {
            const int e2 = r2 * 4;
            j2  = r2 / 19;
            i02 = e2 - j2 * WW;
            qx = __builtin_nontemporal_load((const v4f*)(base + e2));
            qy = __builtin_nontemporal_load((const v4f*)(base + HWSZ + e2));
            qw = __builtin_nontemporal_load((const v4f*)(base + 2 * HWSZ + e2));
            qh = __builtin_nontemporal_load((const v4f*)(base + 3 * HWSZ + e2));
            qc = __builtin_nontemporal_load((const v4f*)(base + 4 * HWSZ + e2));
        }

        const bool rh1 = anchit && (j == gj) && (c.gi >= i0) && (c.gi < i0 + 4);
        proc4(px, py, pw, ph, pc, i0, j, rh1, c, ax, ay, aw_, ah_, ac);
        if (has2) {
            const bool rh2 = anchit && (j2 == gj) && (c.gi >= i02) && (c.gi < i02 + 4);
            proc4(qx, qy, qw, qh, qc, i02, j2, rh2, c, ax, ay, aw_, ah_, ac);
        }
    }

    // block reduction: wave shuffle -> LDS -> per-block partial store (NO atomics)
    __shared__ float sred[4][5];
    int lane = threadIdx.x & 63;
    int wid  = threadIdx.x >> 6;
    float vals[5] = {ax, ay, aw_, ah_, ac};
#pragma unroll
    for (int v = 0; v < 5; ++v) {
        float x = vals[v];
#pragma unroll
        for (int off = 32; off > 0; off >>= 1) x += __shfl_down(x, off, 64);
        if (lane == 0) sred[wid][v] = x;
    }
    __syncthreads();
    if (threadIdx.x < 5) {
        float s = sred[0][threadIdx.x] + sred[1][threadIdx.x] +
                  sred[2][threadIdx.x] + sred[3][threadIdx.x];
        ws[PART_OFF + blockIdx.x * 8 + threadIdx.x] = s;
    }
}

// Reduce NBLK x 5 partials and write the 6 outputs.
__global__ __launch_bounds__(256) void
reduce_finish(const float* __restrict__ ws, float* __restrict__ out) {
    float s0 = 0.f, s1 = 0.f, s2 = 0.f, s3 = 0.f, s4 = 0.f;
    for (int i = threadIdx.x; i < NBLK; i += 256) {
        const float* p = ws + PART_OFF + i * 8;
        s0 += p[0]; s1 += p[1]; s2 += p[2]; s3 += p[3]; s4 += p[4];
    }
    __shared__ float sred[4][5];
    int lane = threadIdx.x & 63;
    int wid  = threadIdx.x >> 6;
    float vals[5] = {s0, s1, s2, s3, s4};
#pragma unroll
    for (int v = 0; v < 5; ++v) {
        float x = vals[v];
#pragma unroll
        for (int off = 32; off > 0; off >>= 1) x += __shfl_down(x, off, 64);
        if (lane == 0) sred[wid][v] = x;
    }
    __syncthreads();
    if (threadIdx.x == 0) {
        float lx = (sred[0][0] + sred[1][0] + sred[2][0] + sred[3][0]) * 0.5f;
        float ly = (sred[0][1] + sred[1][1] + sred[2][1] + sred[3][1]) * 0.5f;
        float lw = (sred[0][2] + sred[1][2] + sred[2][2] + sred[3][2]) * 0.5f;
        float lh = (sred[0][3] + sred[1][3] + sred[2][3] + sred[3][3]) * 0.5f;
        float lc = (sred[0][4] + sred[1][4] + sred[2][4] + sred[3][4]) * 0.5f;
        out[0] = lx + ly + lw + lh + lc;
        out[1] = lx;
        out[2] = ly;
        out[3] = lw;
        out[4] = lh;
        out[5] = lc;
    }
}

extern "C" void kernel_launch(void* const* d_in, const int* in_sizes, int n_in,
                              void* d_out, int out_size, void* d_ws, size_t ws_size,
                              hipStream_t stream) {
    const float* pred   = (const float*)d_in[0];
    const float* target = (const float*)d_in[1];
    float* ws  = (float*)d_ws;
    float* out = (float*)d_out;
    int bs = in_sizes[1] / 4;   // 512

    prep_kernel<<<1, 512, 0, stream>>>(target, ws, bs);
    region_loss_main<<<NBLK, 256, 0, stream>>>(pred, ws);
    reduce_finish<<<1, 256, 0, stream>>>(ws, out);
}